// Round 1
// baseline (580.321 us; speedup 1.0000x reference)
//
#include <hip/hip_runtime.h>

#define H       128
#define NPTS    512
#define NBATCH  4
#define BLOCK   256
#define WAVES   4          // BLOCK/64
#define PW      8          // pairs per wave per chunk
#define CHUNKS  (NPTS / (WAVES * PW))   // 16

__device__ __forceinline__ float fast_rcp(float x) { return __builtin_amdgcn_rcpf(x); }

__device__ __forceinline__ float silu_f(float x) {
    // x * sigmoid(x) = x / (1 + exp(-x)); limits: -inf -> -0*large = 0, +inf -> x. OK.
    float e = __expf(-x);
    return x * fast_rcp(1.0f + e);
}

__device__ __forceinline__ unsigned int bf16_rne(float f) {
    unsigned int u = __float_as_uint(f);
    return (u + 0x7fffu + ((u >> 16) & 1u)) >> 16;
}

__global__ __launch_bounds__(BLOCK) void discovery_forces(
    const float* __restrict__ pos, const float* __restrict__ W1,
    const float* __restrict__ b1,  const float* __restrict__ W2,
    const float* __restrict__ b2,  const float* __restrict__ W3,
    const float* __restrict__ b3,  float* __restrict__ out)
{
    // W2 packed as bf16 pairs: W2s[j*64 + l] = bf16(W2[j][2l]) | bf16(W2[j][2l+1])<<16
    __shared__ unsigned int W2s[H * H / 2];          // 32 KB
    __shared__ float W1s[2 * H];                     // 1 KB
    __shared__ float b1s[H], b2s[H], W3s[H];         // 1.5 KB
    __shared__ float h1s[WAVES][H][PW];              // 16 KB
    __shared__ float fred[WAVES][3];

    const int tid  = threadIdx.x;
    const int lane = tid & 63;
    const int w    = tid >> 6;

    // ---- stage weights ----
    {
        const float2* src = (const float2*)W2;       // pairs (k, k+1) of row j
        #pragma unroll
        for (int r = 0; r < (H * H / 2) / BLOCK; ++r) {
            int idx = r * BLOCK + tid;               // idx = j*64 + pairIdx
            float2 v = src[idx];
            W2s[idx] = bf16_rne(v.x) | (bf16_rne(v.y) << 16);
        }
        if (tid < 2 * H) W1s[tid] = W1[tid];
        if (tid < H) { b1s[tid] = b1[tid]; b2s[tid] = b2[tid]; W3s[tid] = W3[tid]; }
    }

    const int row = blockIdx.x;                      // b*512 + i
    const int b   = row >> 9;
    const int i   = row & (NPTS - 1);
    const float pix = pos[row * 3 + 0];
    const float piy = pos[row * 3 + 1];
    const float piz = pos[row * 3 + 2];
    const float b3v = b3[0];

    __syncthreads();

    // hoisted per-lane weight slices
    const int   k0   = 2 * lane;
    const float w1d0 = W1s[lane],      w1i0 = W1s[H + lane],      b10 = b1s[lane];
    const float w1d1 = W1s[lane + 64], w1i1 = W1s[H + lane + 64], b11 = b1s[lane + 64];
    const float b20  = b2s[k0], b21 = b2s[k0 + 1];
    const float w30  = W3s[k0], w31 = W3s[k0 + 1];

    float fx = 0.f, fy = 0.f, fz = 0.f;

    for (int c = 0; c < CHUNKS; ++c) {
        const int j0 = c * (WAVES * PW) + w * PW;

        // ---- per-pair geometry (wave-uniform values, computed redundantly per lane) ----
        float dx8[PW], dy8[PW], dz8[PW], d8[PW], in8[PW], rin8[PW];
        #pragma unroll
        for (int p = 0; p < PW; ++p) {
            const int j = j0 + p;
            const float* pj = pos + (b * NPTS + j) * 3;
            float dx = pix - pj[0], dy = piy - pj[1], dz = piz - pj[2];
            float s = dx * dx + dy * dy + dz * dz;
            float dist  = __builtin_amdgcn_sqrtf(s);
            float dsafe = fminf(fmaxf(dist, 1e-4f), 50.0f);
            d8[p]  = dsafe;
            in8[p] = fast_rcp(dsafe);
            dx8[p] = dx; dy8[p] = dy; dz8[p] = dz;
            // mask: diagonal and exactly-coincident points contribute zero force
            rin8[p] = (s > 0.0f && j != i) ? fast_rcp(fmaxf(dist, 1e-6f)) : 0.0f;
        }

        __syncthreads();   // protect h1s from previous chunk's readers

        // ---- layer 1: h1[k][p] = silu(d*W1[0][k] + inv*W1[1][k] + b1[k]) ----
        #pragma unroll
        for (int kk = 0; kk < 2; ++kk) {
            const float wa = kk ? w1d1 : w1d0;
            const float wb = kk ? w1i1 : w1i0;
            const float bb = kk ? b11  : b10;
            const int k = lane + kk * 64;
            float v[PW];
            #pragma unroll
            for (int p = 0; p < PW; ++p)
                v[p] = silu_f(fmaf(d8[p], wa, fmaf(in8[p], wb, bb)));
            float4* dst = (float4*)&h1s[w][k][0];
            dst[0] = make_float4(v[0], v[1], v[2], v[3]);
            dst[1] = make_float4(v[4], v[5], v[6], v[7]);
        }

        __syncthreads();   // h1s visible wave-wide

        // ---- layer 2: lane computes h2[k0], h2[k0+1] for all 8 pairs ----
        float acc0[PW], acc1[PW];
        #pragma unroll
        for (int p = 0; p < PW; ++p) { acc0[p] = 0.f; acc1[p] = 0.f; }

        #pragma unroll 4
        for (int j = 0; j < H; ++j) {
            const float4 ha = *(const float4*)&h1s[w][j][0];   // pairs 0..3 (broadcast)
            const float4 hb = *(const float4*)&h1s[w][j][4];   // pairs 4..7 (broadcast)
            const unsigned int u = W2s[j * 64 + lane];         // bf16x2, 2-way bank (free)
            const float wx = __uint_as_float(u << 16);          // W2[j][k0]
            const float wy = __uint_as_float(u & 0xffff0000u);  // W2[j][k0+1]
            acc0[0] = fmaf(ha.x, wx, acc0[0]); acc1[0] = fmaf(ha.x, wy, acc1[0]);
            acc0[1] = fmaf(ha.y, wx, acc0[1]); acc1[1] = fmaf(ha.y, wy, acc1[1]);
            acc0[2] = fmaf(ha.z, wx, acc0[2]); acc1[2] = fmaf(ha.z, wy, acc1[2]);
            acc0[3] = fmaf(ha.w, wx, acc0[3]); acc1[3] = fmaf(ha.w, wy, acc1[3]);
            acc0[4] = fmaf(hb.x, wx, acc0[4]); acc1[4] = fmaf(hb.x, wy, acc1[4]);
            acc0[5] = fmaf(hb.y, wx, acc0[5]); acc1[5] = fmaf(hb.y, wy, acc1[5]);
            acc0[6] = fmaf(hb.z, wx, acc0[6]); acc1[6] = fmaf(hb.z, wy, acc1[6]);
            acc0[7] = fmaf(hb.w, wx, acc0[7]); acc1[7] = fmaf(hb.w, wy, acc1[7]);
        }

        // ---- layer 3 partials + wave reduction -> mag per pair ----
        float part[PW];
        #pragma unroll
        for (int p = 0; p < PW; ++p)
            part[p] = silu_f(acc0[p] + b20) * w30 + silu_f(acc1[p] + b21) * w31;

        #pragma unroll
        for (int off = 32; off >= 1; off >>= 1) {
            #pragma unroll
            for (int p = 0; p < PW; ++p)
                part[p] += __shfl_xor(part[p], off);
        }

        // ---- force accumulation ----
        #pragma unroll
        for (int p = 0; p < PW; ++p) {
            float f = (part[p] + b3v) * rin8[p];
            fx = fmaf(f, dx8[p], fx);
            fy = fmaf(f, dy8[p], fy);
            fz = fmaf(f, dz8[p], fz);
        }
    }

    // ---- cross-wave reduction, one row of out per block ----
    if (lane == 0) { fred[w][0] = fx; fred[w][1] = fy; fred[w][2] = fz; }
    __syncthreads();
    if (tid < 3) {
        float s = 0.f;
        #pragma unroll
        for (int ww = 0; ww < WAVES; ++ww) s += fred[ww][tid];
        out[row * 3 + tid] = s;
    }
}

extern "C" void kernel_launch(void* const* d_in, const int* in_sizes, int n_in,
                              void* d_out, int out_size, void* d_ws, size_t ws_size,
                              hipStream_t stream) {
    const float* pos = (const float*)d_in[0];
    const float* W1  = (const float*)d_in[1];
    const float* b1  = (const float*)d_in[2];
    const float* W2  = (const float*)d_in[3];
    const float* b2  = (const float*)d_in[4];
    const float* W3  = (const float*)d_in[5];
    const float* b3  = (const float*)d_in[6];
    float* out = (float*)d_out;

    dim3 grid(NBATCH * NPTS);
    dim3 block(BLOCK);
    hipLaunchKernelGGL(discovery_forces, grid, block, 0, stream,
                       pos, W1, b1, W2, b2, W3, b3, out);
}

// Round 2
// 97.862 us; speedup vs baseline: 5.9300x; 5.9300x over previous
//
#include <hip/hip_runtime.h>

#define H       128
#define NPTS    512
#define NBATCH  4
#define BLOCK   256
#define WAVES   4
#define PW      8
#define CHUNKS  (NPTS / (WAVES * PW))

// ---- distance->magnitude table parameters ----
// t = log2(dist_safe), dist_safe in [1e-4, 50] (the reference's clip range)
#define TCOUNT  32768                      // intervals
#define T0      (-13.2877123795f)          // log2(1e-4)
#define TRANGE  (18.9315685693f)           // log2(50) - log2(1e-4)
#define TABLE_BYTES (2u * TCOUNT * 4u)     // float2-duplicated table

__device__ __forceinline__ float fast_rcp(float x) { return __builtin_amdgcn_rcpf(x); }

// accurate silu for the table build (matches jax.nn.silu in fp32)
__device__ __forceinline__ float silu_acc(float x) {
    return x / (1.0f + expf(-x));
}

// faster silu used only by the fallback kernel
__device__ __forceinline__ float silu_f(float x) {
    float e = __expf(-x);
    return x * fast_rcp(1.0f + e);
}

__device__ __forceinline__ unsigned int bf16_rne(float f) {
    unsigned int u = __float_as_uint(f);
    return (u + 0x7fffu + ((u >> 16) & 1u)) >> 16;
}

// ============================================================================
// Kernel 1: build the magnitude table.  g(d) = MLP([clip(d), 1/clip(d)]) + b3,
// sampled at t_k = T0 + k*TRANGE/TCOUNT, k = 0..TCOUNT.  Stored duplicated:
// tab[2k] = g_k, tab[2k+1] = g_{k+1}  (one dwordx2 load per lookup).
// Wave structure: 8 samples per wave, lane owns output channels (2l, 2l+1),
// W2 read from global (L2-resident, coalesced float2), all fp32.
// ============================================================================
__global__ __launch_bounds__(BLOCK) void build_mag_table(
    const float* __restrict__ W1, const float* __restrict__ b1,
    const float* __restrict__ W2, const float* __restrict__ b2,
    const float* __restrict__ W3, const float* __restrict__ b3,
    float* __restrict__ tab)
{
    __shared__ float W1s[2 * H];
    __shared__ float b1s[H], b2s[H], W3s[H];
    __shared__ float h1s[WAVES][H][PW];

    const int tid  = threadIdx.x;
    const int lane = tid & 63;
    const int w    = tid >> 6;

    if (tid < 2 * H) W1s[tid] = W1[tid];
    if (tid < H) { b1s[tid] = b1[tid]; b2s[tid] = b2[tid]; W3s[tid] = W3[tid]; }

    const float b3v = b3[0];
    const int base  = blockIdx.x * (WAVES * PW) + w * PW;

    __syncthreads();

    // sample distances (redundant per lane — cheap)
    float d8[PW], in8[PW];
    #pragma unroll
    for (int p = 0; p < PW; ++p) {
        int k = base + p; if (k > TCOUNT) k = TCOUNT;
        float t = fmaf((float)k, TRANGE / (float)TCOUNT, T0);
        float d = exp2f(t);
        float ds = fminf(fmaxf(d, 1e-4f), 50.0f);
        d8[p]  = ds;
        in8[p] = 1.0f / ds;   // IEEE divide — table must be accurate
    }

    // layer 1: lane computes channels (lane, lane+64) for its wave's 8 samples
    #pragma unroll
    for (int kk = 0; kk < 2; ++kk) {
        const int ch = lane + kk * 64;
        const float wa = W1s[ch], wb = W1s[H + ch], bb = b1s[ch];
        float v[PW];
        #pragma unroll
        for (int p = 0; p < PW; ++p)
            v[p] = silu_acc(fmaf(d8[p], wa, fmaf(in8[p], wb, bb)));
        float4* dst = (float4*)&h1s[w][ch][0];
        dst[0] = make_float4(v[0], v[1], v[2], v[3]);
        dst[1] = make_float4(v[4], v[5], v[6], v[7]);
    }

    __syncthreads();

    // layer 2: lane owns channels k0=2*lane, 2*lane+1; W2 from global (fp32)
    const int k0 = 2 * lane;
    float acc0[PW], acc1[PW];
    #pragma unroll
    for (int p = 0; p < PW; ++p) { acc0[p] = 0.f; acc1[p] = 0.f; }

    const float2* w2v = (const float2*)W2;   // w2v[j*64 + lane] = (W2[j][2l], W2[j][2l+1])
    #pragma unroll 4
    for (int j = 0; j < H; ++j) {
        const float4 ha = *(const float4*)&h1s[w][j][0];
        const float4 hb = *(const float4*)&h1s[w][j][4];
        const float2 ww = w2v[j * 64 + lane];
        const float wx = ww.x, wy = ww.y;
        acc0[0] = fmaf(ha.x, wx, acc0[0]); acc1[0] = fmaf(ha.x, wy, acc1[0]);
        acc0[1] = fmaf(ha.y, wx, acc0[1]); acc1[1] = fmaf(ha.y, wy, acc1[1]);
        acc0[2] = fmaf(ha.z, wx, acc0[2]); acc1[2] = fmaf(ha.z, wy, acc1[2]);
        acc0[3] = fmaf(ha.w, wx, acc0[3]); acc1[3] = fmaf(ha.w, wy, acc1[3]);
        acc0[4] = fmaf(hb.x, wx, acc0[4]); acc1[4] = fmaf(hb.x, wy, acc1[4]);
        acc0[5] = fmaf(hb.y, wx, acc0[5]); acc1[5] = fmaf(hb.y, wy, acc1[5]);
        acc0[6] = fmaf(hb.z, wx, acc0[6]); acc1[6] = fmaf(hb.z, wy, acc1[6]);
        acc0[7] = fmaf(hb.w, wx, acc0[7]); acc1[7] = fmaf(hb.w, wy, acc1[7]);
    }

    // layer 3 partials + full-wave butterfly reduction
    const float b20 = b2s[k0], b21 = b2s[k0 + 1];
    const float w30 = W3s[k0], w31 = W3s[k0 + 1];
    float part[PW];
    #pragma unroll
    for (int p = 0; p < PW; ++p)
        part[p] = silu_acc(acc0[p] + b20) * w30 + silu_acc(acc1[p] + b21) * w31;

    #pragma unroll
    for (int off = 32; off >= 1; off >>= 1) {
        #pragma unroll
        for (int p = 0; p < PW; ++p)
            part[p] += __shfl_xor(part[p], off);
    }

    if (lane == 0) {
        #pragma unroll
        for (int p = 0; p < PW; ++p) {
            int k = base + p; if (k > TCOUNT) k = TCOUNT;
            float g = part[p] + b3v;
            if (k < TCOUNT) tab[2 * k] = g;          // tab2[k].x
            if (k >= 1)     tab[2 * k - 1] = g;      // tab2[k-1].y
        }
    }
}

// ============================================================================
// Kernel 2: pairwise forces via table lookup.
// One block per output row (b,i); thread t handles j = t and j = t+256.
// ============================================================================
__global__ __launch_bounds__(BLOCK) void eval_forces(
    const float* __restrict__ pos, const float* __restrict__ tab,
    float* __restrict__ out)
{
    __shared__ float poss[NPTS * 3];
    __shared__ float fred[WAVES][3];

    const int tid  = threadIdx.x;
    const int lane = tid & 63;
    const int w    = tid >> 6;
    const int row  = blockIdx.x;
    const int b    = row >> 9;
    const int i    = row & (NPTS - 1);

    const float* pb = pos + b * NPTS * 3;
    #pragma unroll
    for (int k = tid; k < NPTS * 3; k += BLOCK) poss[k] = pb[k];
    __syncthreads();

    const float pix = poss[3 * i + 0];
    const float piy = poss[3 * i + 1];
    const float piz = poss[3 * i + 2];

    const float INVH = (float)TCOUNT / TRANGE;
    const float XOFF = -T0 * ((float)TCOUNT / TRANGE);
    const float2* tab2 = (const float2*)tab;

    float fx = 0.f, fy = 0.f, fz = 0.f;

    #pragma unroll
    for (int jj = 0; jj < 2; ++jj) {
        const int j = tid + jj * BLOCK;
        const float dx = pix - poss[3 * j + 0];
        const float dy = piy - poss[3 * j + 1];
        const float dz = piz - poss[3 * j + 2];
        const float s  = fmaf(dx, dx, fmaf(dy, dy, dz * dz));
        if (s > 0.0f && j != i) {
            const float rs = rsqrtf(s);
            const float d  = s * rs;                       // = sqrt(s)
            const float ds = fminf(fmaxf(d, 1e-4f), 50.0f);
            float x = fmaf(__log2f(ds), INVH, XOFF);
            x = fminf(fmaxf(x, 0.0f), (float)TCOUNT - 0.001f);
            const int   k  = (int)x;
            const float fr = x - (float)k;
            const float2 g = tab2[k];
            const float mag = fmaf(fr, g.y - g.x, g.x);
            const float f   = mag * fminf(rs, 1e6f);       // mag * 1/clip(d,1e-6)
            fx = fmaf(f, dx, fx);
            fy = fmaf(f, dy, fy);
            fz = fmaf(f, dz, fz);
        }
    }

    #pragma unroll
    for (int off = 32; off >= 1; off >>= 1) {
        fx += __shfl_xor(fx, off);
        fy += __shfl_xor(fy, off);
        fz += __shfl_xor(fz, off);
    }
    if (lane == 0) { fred[w][0] = fx; fred[w][1] = fy; fred[w][2] = fz; }
    __syncthreads();
    if (tid < 3) {
        float s = 0.f;
        #pragma unroll
        for (int ww = 0; ww < WAVES; ++ww) s += fred[ww][tid];
        out[row * 3 + tid] = s;
    }
}

// ============================================================================
// Fallback: round-1 direct kernel (used only if ws_size is too small)
// ============================================================================
__global__ __launch_bounds__(BLOCK) void discovery_forces_direct(
    const float* __restrict__ pos, const float* __restrict__ W1,
    const float* __restrict__ b1,  const float* __restrict__ W2,
    const float* __restrict__ b2,  const float* __restrict__ W3,
    const float* __restrict__ b3,  float* __restrict__ out)
{
    __shared__ unsigned int W2s[H * H / 2];
    __shared__ float W1s[2 * H];
    __shared__ float b1s[H], b2s[H], W3s[H];
    __shared__ float h1s[WAVES][H][PW];
    __shared__ float fred[WAVES][3];

    const int tid  = threadIdx.x;
    const int lane = tid & 63;
    const int w    = tid >> 6;

    {
        const float2* src = (const float2*)W2;
        #pragma unroll
        for (int r = 0; r < (H * H / 2) / BLOCK; ++r) {
            int idx = r * BLOCK + tid;
            float2 v = src[idx];
            W2s[idx] = bf16_rne(v.x) | (bf16_rne(v.y) << 16);
        }
        if (tid < 2 * H) W1s[tid] = W1[tid];
        if (tid < H) { b1s[tid] = b1[tid]; b2s[tid] = b2[tid]; W3s[tid] = W3[tid]; }
    }

    const int row = blockIdx.x;
    const int b   = row >> 9;
    const int i   = row & (NPTS - 1);
    const float pix = pos[row * 3 + 0];
    const float piy = pos[row * 3 + 1];
    const float piz = pos[row * 3 + 2];
    const float b3v = b3[0];

    __syncthreads();

    const int   k0   = 2 * lane;
    const float w1d0 = W1s[lane],      w1i0 = W1s[H + lane],      b10 = b1s[lane];
    const float w1d1 = W1s[lane + 64], w1i1 = W1s[H + lane + 64], b11 = b1s[lane + 64];
    const float b20  = b2s[k0], b21 = b2s[k0 + 1];
    const float w30  = W3s[k0], w31 = W3s[k0 + 1];

    float fx = 0.f, fy = 0.f, fz = 0.f;

    for (int c = 0; c < CHUNKS; ++c) {
        const int j0 = c * (WAVES * PW) + w * PW;
        float dx8[PW], dy8[PW], dz8[PW], d8[PW], in8[PW], rin8[PW];
        #pragma unroll
        for (int p = 0; p < PW; ++p) {
            const int j = j0 + p;
            const float* pj = pos + (b * NPTS + j) * 3;
            float dx = pix - pj[0], dy = piy - pj[1], dz = piz - pj[2];
            float s = dx * dx + dy * dy + dz * dz;
            float dist  = __builtin_amdgcn_sqrtf(s);
            float dsafe = fminf(fmaxf(dist, 1e-4f), 50.0f);
            d8[p]  = dsafe;
            in8[p] = fast_rcp(dsafe);
            dx8[p] = dx; dy8[p] = dy; dz8[p] = dz;
            rin8[p] = (s > 0.0f && j != i) ? fast_rcp(fmaxf(dist, 1e-6f)) : 0.0f;
        }
        __syncthreads();
        #pragma unroll
        for (int kk = 0; kk < 2; ++kk) {
            const float wa = kk ? w1d1 : w1d0;
            const float wb = kk ? w1i1 : w1i0;
            const float bb = kk ? b11  : b10;
            const int k = lane + kk * 64;
            float v[PW];
            #pragma unroll
            for (int p = 0; p < PW; ++p)
                v[p] = silu_f(fmaf(d8[p], wa, fmaf(in8[p], wb, bb)));
            float4* dst = (float4*)&h1s[w][k][0];
            dst[0] = make_float4(v[0], v[1], v[2], v[3]);
            dst[1] = make_float4(v[4], v[5], v[6], v[7]);
        }
        __syncthreads();
        float acc0[PW], acc1[PW];
        #pragma unroll
        for (int p = 0; p < PW; ++p) { acc0[p] = 0.f; acc1[p] = 0.f; }
        #pragma unroll 4
        for (int j = 0; j < H; ++j) {
            const float4 ha = *(const float4*)&h1s[w][j][0];
            const float4 hb = *(const float4*)&h1s[w][j][4];
            const unsigned int u = W2s[j * 64 + lane];
            const float wx = __uint_as_float(u << 16);
            const float wy = __uint_as_float(u & 0xffff0000u);
            acc0[0] = fmaf(ha.x, wx, acc0[0]); acc1[0] = fmaf(ha.x, wy, acc1[0]);
            acc0[1] = fmaf(ha.y, wx, acc0[1]); acc1[1] = fmaf(ha.y, wy, acc1[1]);
            acc0[2] = fmaf(ha.z, wx, acc0[2]); acc1[2] = fmaf(ha.z, wy, acc1[2]);
            acc0[3] = fmaf(ha.w, wx, acc0[3]); acc1[3] = fmaf(ha.w, wy, acc1[3]);
            acc0[4] = fmaf(hb.x, wx, acc0[4]); acc1[4] = fmaf(hb.x, wy, acc1[4]);
            acc0[5] = fmaf(hb.y, wx, acc0[5]); acc1[5] = fmaf(hb.y, wy, acc1[5]);
            acc0[6] = fmaf(hb.z, wx, acc0[6]); acc1[6] = fmaf(hb.z, wy, acc1[6]);
            acc0[7] = fmaf(hb.w, wx, acc0[7]); acc1[7] = fmaf(hb.w, wy, acc1[7]);
        }
        float part[PW];
        #pragma unroll
        for (int p = 0; p < PW; ++p)
            part[p] = silu_f(acc0[p] + b20) * w30 + silu_f(acc1[p] + b21) * w31;
        #pragma unroll
        for (int off = 32; off >= 1; off >>= 1) {
            #pragma unroll
            for (int p = 0; p < PW; ++p)
                part[p] += __shfl_xor(part[p], off);
        }
        #pragma unroll
        for (int p = 0; p < PW; ++p) {
            float f = (part[p] + b3v) * rin8[p];
            fx = fmaf(f, dx8[p], fx);
            fy = fmaf(f, dy8[p], fy);
            fz = fmaf(f, dz8[p], fz);
        }
    }

    if (lane == 0) { fred[w][0] = fx; fred[w][1] = fy; fred[w][2] = fz; }
    __syncthreads();
    if (tid < 3) {
        float s = 0.f;
        #pragma unroll
        for (int ww = 0; ww < WAVES; ++ww) s += fred[ww][tid];
        out[row * 3 + tid] = s;
    }
}

extern "C" void kernel_launch(void* const* d_in, const int* in_sizes, int n_in,
                              void* d_out, int out_size, void* d_ws, size_t ws_size,
                              hipStream_t stream) {
    const float* pos = (const float*)d_in[0];
    const float* W1  = (const float*)d_in[1];
    const float* b1  = (const float*)d_in[2];
    const float* W2  = (const float*)d_in[3];
    const float* b2  = (const float*)d_in[4];
    const float* W3  = (const float*)d_in[5];
    const float* b3  = (const float*)d_in[6];
    float* out = (float*)d_out;

    if (ws_size >= (size_t)TABLE_BYTES) {
        float* tab = (float*)d_ws;
        // build table: (TCOUNT+1) samples, 32 per block
        int nblk = (TCOUNT + 1 + WAVES * PW - 1) / (WAVES * PW);
        hipLaunchKernelGGL(build_mag_table, dim3(nblk), dim3(BLOCK), 0, stream,
                           W1, b1, W2, b2, W3, b3, tab);
        hipLaunchKernelGGL(eval_forces, dim3(NBATCH * NPTS), dim3(BLOCK), 0, stream,
                           pos, tab, out);
    } else {
        hipLaunchKernelGGL(discovery_forces_direct, dim3(NBATCH * NPTS), dim3(BLOCK), 0, stream,
                           pos, W1, b1, W2, b2, W3, b3, out);
    }
}

// Round 3
// 76.256 us; speedup vs baseline: 7.6101x; 1.2833x over previous
//
#include <hip/hip_runtime.h>

#define H       128
#define NPTS    512
#define NBATCH  4
#define BLOCK   256
#define WAVES   4
#define PW      8

// ---- distance->magnitude table ----
// t = log2(dist_safe), dist_safe in [1e-4, 50] (the reference's clip range).
// TSAMP samples t_k = T0 + k*TRANGE/TIVL, k = 0..TIVL; TIVL intervals.
#define TSAMP   8192
#define TIVL    8191
#define T0      (-13.2877123795f)
#define TRANGE  (18.9315685693f)
#define TABLE_FLOATS (2 * TSAMP)
#define TABLE_BYTES  (TABLE_FLOATS * 4u)

__device__ __forceinline__ float fast_rcp(float x) { return __builtin_amdgcn_rcpf(x); }

__device__ __forceinline__ float silu_f(float x) {
    float e = __expf(-x);
    return x * fast_rcp(1.0f + e);
}

// ============================================================================
// Kernel 1: build magnitude table. 256 blocks x 256 thr; block owns 32 samples
// (8 per wave). W2 staged in LDS (fp32, 64 KB) -> hot loop has NO global loads.
// tab duplicated: tab[2k] = g_k, tab[2k+1] = g_{k+1} (one dwordx2 per lookup).
// ============================================================================
__global__ __launch_bounds__(BLOCK) void build_mag_table(
    const float* __restrict__ W1, const float* __restrict__ b1,
    const float* __restrict__ W2, const float* __restrict__ b2,
    const float* __restrict__ W3, const float* __restrict__ b3,
    float* __restrict__ tab)
{
    __shared__ float W2s[H * H];                 // 64 KB
    __shared__ float W1s[2 * H];
    __shared__ float b1s[H], b2s[H], W3s[H];
    __shared__ float h1s[WAVES][H][PW];          // 16 KB (per-wave private)

    const int tid  = threadIdx.x;
    const int lane = tid & 63;
    const int w    = tid >> 6;

    // ---- stage all weights (coalesced float4 for W2) ----
    {
        const float4* src = (const float4*)W2;
        float4* dst = (float4*)W2s;
        #pragma unroll
        for (int r = 0; r < (H * H / 4) / BLOCK; ++r)
            dst[r * BLOCK + tid] = src[r * BLOCK + tid];
        if (tid < 2 * H) W1s[tid] = W1[tid];
        if (tid < H) { b1s[tid] = b1[tid]; b2s[tid] = b2[tid]; W3s[tid] = W3[tid]; }
    }

    const float b3v = b3[0];
    const int base  = blockIdx.x * (WAVES * PW) + w * PW;   // 256*32 = 8192 = TSAMP

    __syncthreads();

    // ---- sample geometry ----
    float d8[PW], in8[PW];
    #pragma unroll
    for (int p = 0; p < PW; ++p) {
        float t  = fmaf((float)(base + p), TRANGE / (float)TIVL, T0);
        float d  = exp2f(t);
        float ds = fminf(fmaxf(d, 1e-4f), 50.0f);
        d8[p]  = ds;
        in8[p] = 1.0f / ds;
    }

    // ---- layer 1: lane owns channels (lane, lane+64) for its wave's 8 samples.
    // h1s[w] is written AND read only by wave w -> no barrier needed. ----
    #pragma unroll
    for (int kk = 0; kk < 2; ++kk) {
        const int ch = lane + kk * 64;
        const float wa = W1s[ch], wb = W1s[H + ch], bb = b1s[ch];
        float v[PW];
        #pragma unroll
        for (int p = 0; p < PW; ++p)
            v[p] = silu_f(fmaf(d8[p], wa, fmaf(in8[p], wb, bb)));
        float4* dst = (float4*)&h1s[w][ch][0];
        dst[0] = make_float4(v[0], v[1], v[2], v[3]);
        dst[1] = make_float4(v[4], v[5], v[6], v[7]);
    }

    // ---- layer 2: lane owns channels k0, k0+1; all operands from LDS ----
    const int k0 = 2 * lane;
    float acc0[PW], acc1[PW];
    #pragma unroll
    for (int p = 0; p < PW; ++p) { acc0[p] = 0.f; acc1[p] = 0.f; }

    #pragma unroll 4
    for (int j = 0; j < H; ++j) {
        const float4 ha = *(const float4*)&h1s[w][j][0];      // broadcast (free)
        const float4 hb = *(const float4*)&h1s[w][j][4];      // broadcast (free)
        const float2 ww = *(const float2*)&W2s[j * H + k0];   // b64, 2-way (free)
        const float wx = ww.x, wy = ww.y;
        acc0[0] = fmaf(ha.x, wx, acc0[0]); acc1[0] = fmaf(ha.x, wy, acc1[0]);
        acc0[1] = fmaf(ha.y, wx, acc0[1]); acc1[1] = fmaf(ha.y, wy, acc1[1]);
        acc0[2] = fmaf(ha.z, wx, acc0[2]); acc1[2] = fmaf(ha.z, wy, acc1[2]);
        acc0[3] = fmaf(ha.w, wx, acc0[3]); acc1[3] = fmaf(ha.w, wy, acc1[3]);
        acc0[4] = fmaf(hb.x, wx, acc0[4]); acc1[4] = fmaf(hb.x, wy, acc1[4]);
        acc0[5] = fmaf(hb.y, wx, acc0[5]); acc1[5] = fmaf(hb.y, wy, acc1[5]);
        acc0[6] = fmaf(hb.z, wx, acc0[6]); acc1[6] = fmaf(hb.z, wy, acc1[6]);
        acc0[7] = fmaf(hb.w, wx, acc0[7]); acc1[7] = fmaf(hb.w, wy, acc1[7]);
    }

    // ---- layer 3 + full-wave butterfly ----
    const float b20 = b2s[k0], b21 = b2s[k0 + 1];
    const float w30 = W3s[k0], w31 = W3s[k0 + 1];
    float part[PW];
    #pragma unroll
    for (int p = 0; p < PW; ++p)
        part[p] = silu_f(acc0[p] + b20) * w30 + silu_f(acc1[p] + b21) * w31;

    #pragma unroll
    for (int off = 32; off >= 1; off >>= 1) {
        #pragma unroll
        for (int p = 0; p < PW; ++p)
            part[p] += __shfl_xor(part[p], off);
    }

    if (lane == 0) {
        #pragma unroll
        for (int p = 0; p < PW; ++p) {
            const int k = base + p;                 // 0..TIVL
            const float g = part[p] + b3v;
            if (k < TIVL) tab[2 * k] = g;           // tab2[k].x
            if (k >= 1)   tab[2 * k - 1] = g;       // tab2[k-1].y
        }
    }
}

// ============================================================================
// Kernel 2: forces. 512 blocks x 256 thr; one ROW per wave (64 lanes x 8 j).
// ============================================================================
__global__ __launch_bounds__(BLOCK) void eval_forces(
    const float* __restrict__ pos, const float* __restrict__ tab,
    float* __restrict__ out)
{
    __shared__ float poss[NPTS * 3];

    const int tid  = threadIdx.x;
    const int lane = tid & 63;
    const int w    = tid >> 6;
    const int row  = blockIdx.x * WAVES + w;     // 512*4 = 2048 rows
    const int b    = row >> 9;                   // same for all 4 waves (4 | 512)
    const int i    = row & (NPTS - 1);

    {
        const float4* src = (const float4*)(pos + b * NPTS * 3);
        float4* dst = (float4*)poss;
        for (int r = tid; r < NPTS * 3 / 4; r += BLOCK) dst[r] = src[r];
    }
    __syncthreads();

    const float pix = poss[3 * i + 0];
    const float piy = poss[3 * i + 1];
    const float piz = poss[3 * i + 2];

    const float INVH = (float)TIVL / TRANGE;
    const float XOFF = -T0 * ((float)TIVL / TRANGE);
    const float2* tab2 = (const float2*)tab;

    float fx = 0.f, fy = 0.f, fz = 0.f;

    #pragma unroll
    for (int k = 0; k < NPTS / 64; ++k) {
        const int j = lane + 64 * k;
        const float dx = pix - poss[3 * j + 0];
        const float dy = piy - poss[3 * j + 1];
        const float dz = piz - poss[3 * j + 2];
        const float s  = fmaf(dx, dx, fmaf(dy, dy, dz * dz));
        const bool ok  = (s > 0.0f) && (j != i);
        const float rs = __builtin_amdgcn_rsqf(fmaxf(s, 1e-30f));
        const float d  = s * rs;
        const float ds = fminf(fmaxf(d, 1e-4f), 50.0f);
        float x = fmaf(__log2f(ds), INVH, XOFF);
        x = fminf(fmaxf(x, 0.0f), (float)TIVL - 0.001f);
        const int   kk = (int)x;
        const float fr = x - (float)kk;
        const float2 g = tab2[kk];
        const float mag = fmaf(fr, g.y - g.x, g.x);
        const float f   = ok ? mag * fminf(rs, 1e6f) : 0.0f;
        fx = fmaf(f, dx, fx);
        fy = fmaf(f, dy, fy);
        fz = fmaf(f, dz, fz);
    }

    #pragma unroll
    for (int off = 32; off >= 1; off >>= 1) {
        fx += __shfl_xor(fx, off);
        fy += __shfl_xor(fy, off);
        fz += __shfl_xor(fz, off);
    }
    if (lane == 0) {
        out[row * 3 + 0] = fx;
        out[row * 3 + 1] = fy;
        out[row * 3 + 2] = fz;
    }
}

extern "C" void kernel_launch(void* const* d_in, const int* in_sizes, int n_in,
                              void* d_out, int out_size, void* d_ws, size_t ws_size,
                              hipStream_t stream) {
    const float* pos = (const float*)d_in[0];
    const float* W1  = (const float*)d_in[1];
    const float* b1  = (const float*)d_in[2];
    const float* W2  = (const float*)d_in[3];
    const float* b2  = (const float*)d_in[4];
    const float* W3  = (const float*)d_in[5];
    const float* b3  = (const float*)d_in[6];
    float* out = (float*)d_out;
    float* tab = (float*)d_ws;

    hipLaunchKernelGGL(build_mag_table, dim3(TSAMP / (WAVES * PW)), dim3(BLOCK), 0, stream,
                       W1, b1, W2, b2, W3, b3, tab);
    hipLaunchKernelGGL(eval_forces, dim3(NBATCH * NPTS / WAVES), dim3(BLOCK), 0, stream,
                       pos, tab, out);
}